// Round 2
// 564.041 us; speedup vs baseline: 1.0818x; 1.0818x over previous
//
#include <hip/hip_runtime.h>
#include <hip/hip_bf16.h>

// Problem: out[M,N] = data[M,K] @ (weight*mask)[N,K]^T + bias[N]
// M = 8192, N = 4096, K = 4096, fp32 in/out, bf16 MFMA internally.
//
// R5: fixes R4's LDS race. R4 staged kt+2 halves into the live buffer on a
// phase schedule that assumed fragment-space == LDS-region-space; waves with
// wm=128 / wn>=128 actually touch the OTHER half every phase, so p3/p2 stages
// clobbered rows re-read at p4/p3 (absmax 3.3, run-to-run divergence).
// New provably race-free 4-phase schedule (per K-tile, 64 tiles of BK=64):
//   p1: ds_read A-mh0 frags (8) + ALL B frags (8)  -> MFMA Q(0,0)
//   p2: stage B-h0(kt+2)                           -> MFMA Q(0,1)
//   p3: ds_read A-mh1 frags (8); stage B-h1(kt+2)  -> MFMA Q(1,1)
//   p4: stage A-h0(kt+2)+A-h1(kt+2); vmcnt(8)      -> MFMA Q(1,0)
// Region-freedom proof: B rows are read ONLY at p1 (all nh held in regs) ->
// stageable from p2. A rows read at p1 (own mh0 quarter) and p3 (mh1) ->
// stageable from p4. Each stage is issued after the barrier that follows the
// region's last read's lgkmcnt(0), so the async LDS-DMA write cannot land
// before the read. vmcnt(8) once per tile: tile kt+1's 8 loads landed, tile
// kt+2's 8 in flight across barriers (T4 counted, never 0 in main loop).
// Quadrant order keeps one A-half live (af 32 + bf 32 + acc 128 VGPR < 256).
// T2 XOR swizzle (pre-swizzled global src, swizzled ds_read), T5 setprio kept.

#define M_TOT 8192
#define N_TOT 4096
#define K_TOT 4096

#define BM 256
#define BN 256
#define BK 64
#define NT (K_TOT / BK)   // 64 K-tiles

typedef __attribute__((ext_vector_type(8))) short short8;
typedef __attribute__((ext_vector_type(4))) float floatx4;

// ---- fp32 -> bf16 round-to-nearest-even ----
__device__ inline unsigned short f2bf(float f) {
    unsigned int u = __builtin_bit_cast(unsigned int, f);
    u += 0x7fffu + ((u >> 16) & 1u);
    return (unsigned short)(u >> 16);
}

// data[M*K] fp32 -> bf16  (exact grid, one float4 per thread)
__global__ __launch_bounds__(256) void cast_data_kernel(const float4* __restrict__ in,
                                                        ushort4* __restrict__ out) {
    int i = blockIdx.x * 256 + threadIdx.x;
    float4 f = in[i];
    ushort4 o;
    o.x = f2bf(f.x); o.y = f2bf(f.y); o.z = f2bf(f.z); o.w = f2bf(f.w);
    out[i] = o;
}

// (weight * mask)[N*K] fp32 -> bf16
__global__ __launch_bounds__(256) void cast_w_kernel(const float4* __restrict__ w,
                                                     const float4* __restrict__ m,
                                                     ushort4* __restrict__ out) {
    int i = blockIdx.x * 256 + threadIdx.x;
    float4 a = w[i];
    float4 b = m[i];
    ushort4 o;
    o.x = f2bf(a.x * b.x); o.y = f2bf(a.y * b.y);
    o.z = f2bf(a.z * b.z); o.w = f2bf(a.w * b.w);
    out[i] = o;
}

// ---- async global->LDS, 16B per lane (LDS dst linear: base + lane*16) ----
__device__ inline void load_lds16(const unsigned short* g, unsigned short* l) {
    __builtin_amdgcn_global_load_lds(
        (__attribute__((address_space(1))) void*)(const_cast<unsigned short*>(g)),
        (__attribute__((address_space(3))) void*)(l),
        16, 0, 0);
}

#define BAR()   __builtin_amdgcn_s_barrier()
#define SB0()   __builtin_amdgcn_sched_barrier(0)
#define LGKM0() do { asm volatile("s_waitcnt lgkmcnt(0)" ::: "memory"); SB0(); } while (0)
#define VM8()   asm volatile("s_waitcnt vmcnt(8)" ::: "memory")
#define VM0()   asm volatile("s_waitcnt vmcnt(0)" ::: "memory")

__global__ __launch_bounds__(512, 2) void gemm_bt_kernel(const unsigned short* __restrict__ A,
                                                         const unsigned short* __restrict__ W,
                                                         const float* __restrict__ bias,
                                                         float* __restrict__ out) {
    // 2 buffers x 256 rows x 64 cols bf16 for A and B: 64 KiB + 64 KiB.
    __shared__ __align__(16) unsigned short As[2 * BM * BK];
    __shared__ __align__(16) unsigned short Bs[2 * BN * BK];

    const int t = threadIdx.x;
    const int m0 = blockIdx.y * BM;
    const int n0 = blockIdx.x * BN;

    const int lane  = t & 63;
    const int wv    = t >> 6;            // wave 0..7
    const int wm    = (wv >> 2) * 128;   // wave m-offset (0/128)
    const int wn    = (wv & 3) * 64;     // wave n-offset (0/64/128/192)
    const int row16 = lane & 15;
    const int quad  = lane >> 4;         // k-chunk group of this lane
    const int rx    = row16 & 7;         // read-side swizzle factor (== row&7)

    // ---- staging geometry (identical to proven R3 pattern, BK=64) ----
    // half-tile = 128 rows x 64 cols = 128 rows x 8 slots(16B) = 1024 chunks;
    // thread t writes linear LDS chunks t and t+512. Phys slot (t&7) of row
    // (t>>3) must hold logical slot (t&7)^(row&7) => pre-swizzle the GLOBAL
    // source (LDS dst stays linear as global_load_lds requires). Chunk t+512
    // is row+64: (row+64)&7 == row&7, same slot formula.
    const int srow  = t >> 3;                       // 0..63
    const int lslot = (t & 7) ^ (srow & 7);
    const size_t thr_off = (size_t)srow * K_TOT + (size_t)lslot * 8;  // ushorts

    const unsigned short* Ag = A + (size_t)m0 * K_TOT + thr_off;
    const unsigned short* Bg = W + (size_t)n0 * K_TOT + thr_off;

    auto stageA = [&](int ts, int h) {
        const unsigned short* s = Ag + (size_t)(h * 128) * K_TOT + ts * BK;
        unsigned short* d = As + (ts & 1) * (BM * BK) + h * (128 * BK) + t * 8;
        load_lds16(s, d);
        load_lds16(s + (size_t)64 * K_TOT, d + 512 * 8);
    };
    auto stageB = [&](int ts, int h) {
        const unsigned short* s = Bg + (size_t)(h * 128) * K_TOT + ts * BK;
        unsigned short* d = Bs + (ts & 1) * (BN * BK) + h * (128 * BK) + t * 8;
        load_lds16(s, d);
        load_lds16(s + (size_t)64 * K_TOT, d + 512 * 8);
    };

    // ---- fragments: one A-half live at a time; both B halves held ----
    short8 af[4][2];      // current A m-half: 4 frags x 2 k-steps (32 VGPR)
    short8 bf[2][2][2];   // [nh][j][ks] all B for the tile      (32 VGPR)

    auto readA_half = [&](int buf, int mh) {
#pragma unroll
        for (int i = 0; i < 4; i++) {
            const unsigned short* base =
                As + buf * (BM * BK) + (wm + mh * 64 + i * 16 + row16) * BK;
            af[i][0] = *(const short8*)(base + ((quad ^ rx) << 3));
            af[i][1] = *(const short8*)(base + (((4 + quad) ^ rx) << 3));
        }
    };
    auto readB_all = [&](int buf) {
#pragma unroll
        for (int nh = 0; nh < 2; nh++)
#pragma unroll
            for (int j = 0; j < 2; j++) {
                const unsigned short* base =
                    Bs + buf * (BN * BK) + (wn + nh * 32 + j * 16 + row16) * BK;
                bf[nh][j][0] = *(const short8*)(base + ((quad ^ rx) << 3));
                bf[nh][j][1] = *(const short8*)(base + (((4 + quad) ^ rx) << 3));
            }
    };

    floatx4 acc[8][4];
#pragma unroll
    for (int i = 0; i < 8; i++)
#pragma unroll
        for (int j = 0; j < 4; j++) {
            floatx4 z = {0.0f, 0.0f, 0.0f, 0.0f};
            acc[i][j] = z;
        }

    auto mmaQ = [&](int mh, int nh) {
        __builtin_amdgcn_s_setprio(1);
#pragma unroll
        for (int i = 0; i < 4; i++)
#pragma unroll
            for (int j = 0; j < 2; j++)
#pragma unroll
                for (int ks = 0; ks < 2; ks++)
                    acc[mh * 4 + i][nh * 2 + j] = __builtin_amdgcn_mfma_f32_16x16x32_bf16(
                        af[i][ks], bf[nh][j][ks], acc[mh * 4 + i][nh * 2 + j], 0, 0, 0);
        __builtin_amdgcn_s_setprio(0);
    };

    // mode 0: full staging (stage kt+2, vmcnt(8))
    // mode 1: no staging, vmcnt(0) at p4 (tile NT-2)
    // mode 2: no staging, no wait, no trailing barrier (tile NT-1)
    auto tile = [&](int kt, int mode) {
        const int buf = kt & 1;
        // p1: A-mh0 + all B  -> Q(0,0)
        readA_half(buf, 0);
        readB_all(buf);
        BAR(); LGKM0();
        mmaQ(0, 0);
        BAR();
        // p2: stage B-h0(kt+2) -> Q(0,1)   (B fully read at p1)
        if (mode == 0) stageB(kt + 2, 0);
        BAR(); SB0();
        mmaQ(0, 1);
        BAR();
        // p3: A-mh1; stage B-h1(kt+2) -> Q(1,1)
        readA_half(buf, 1);
        if (mode == 0) stageB(kt + 2, 1);
        BAR(); LGKM0();
        mmaQ(1, 1);
        BAR();
        // p4: stage A both halves (A fully read after p3); counted wait -> Q(1,0)
        if (mode == 0) { stageA(kt + 2, 0); stageA(kt + 2, 1); VM8(); }
        if (mode == 1) { VM0(); }
        BAR(); SB0();
        mmaQ(1, 0);
        if (mode != 2) BAR();
    };

    // ---- prologue: stage tiles 0 and 1 (16 loads); oldest 8 (tile 0) landed
    stageB(0, 0); stageB(0, 1); stageA(0, 0); stageA(0, 1);
    stageB(1, 0); stageB(1, 1); stageA(1, 0); stageA(1, 1);
    VM8();
    BAR();

    for (int kt = 0; kt < NT - 2; ++kt)
        tile(kt, 0);
    tile(NT - 2, 1);
    tile(NT - 1, 2);

    // ---- epilogue: C/D layout (16x16x32): col = lane&15, row = (lane>>4)*4 + reg
    float bb[4];
#pragma unroll
    for (int j = 0; j < 4; j++)
        bb[j] = bias[n0 + wn + j * 16 + row16];

#pragma unroll
    for (int ai = 0; ai < 8; ai++) {
        const int gm = m0 + wm + ai * 16 + quad * 4;
#pragma unroll
        for (int bj = 0; bj < 4; bj++) {
            const int gn = n0 + wn + bj * 16 + row16;
            float* o = out + (size_t)gm * N_TOT + gn;
#pragma unroll
            for (int r = 0; r < 4; r++)
                o[(size_t)r * N_TOT] = acc[ai][bj][r] + bb[bj];
        }
    }
}

extern "C" void kernel_launch(void* const* d_in, const int* in_sizes, int n_in,
                              void* d_out, int out_size, void* d_ws, size_t ws_size,
                              hipStream_t stream) {
    const float* data   = (const float*)d_in[0];   // [4,2048,4096]
    const float* weight = (const float*)d_in[1];   // [4096,4096]
    const float* w_mask = (const float*)d_in[2];   // [4096,4096]
    const float* bias_p = (const float*)d_in[3];   // [4096]
    float* out = (float*)d_out;

    // Workspace layout: A_bf16 [M*K] then W_bf16 [N*K]  (96 MB total)
    unsigned short* a_bf = (unsigned short*)d_ws;
    unsigned short* w_bf = a_bf + (size_t)M_TOT * K_TOT;

    cast_data_kernel<<<(M_TOT * K_TOT) / (256 * 4), 256, 0, stream>>>(
        (const float4*)data, (ushort4*)a_bf);
    cast_w_kernel<<<(N_TOT * K_TOT) / (256 * 4), 256, 0, stream>>>(
        (const float4*)weight, (const float4*)w_mask, (ushort4*)w_bf);

    dim3 grid(N_TOT / BN, M_TOT / BM);   // (16, 32)
    gemm_bt_kernel<<<grid, 512, 0, stream>>>(a_bf, w_bf, bias_p, out);
}

// Round 3
// 529.864 us; speedup vs baseline: 1.1516x; 1.0645x over previous
//
#include <hip/hip_runtime.h>
#include <hip/hip_bf16.h>

// Problem: out[M,N] = data[M,K] @ (weight*mask)[N,K]^T + bias[N]
// M = 8192, N = 4096, K = 4096, fp32 in/out, bf16 MFMA internally.
//
// R6: R5 + one-phase-ahead ds_read software pipeline.
// R5 post-mortem: 42% MfmaUtil, ~5200 cyc/tile vs 2480 MFMA floor — each
// phase serialized {ds_read drain at lgkmcnt(0)} before MFMA. Fix: every
// phase issues the NEXT quadrant's fragment reads, MFMA runs on operands
// read one phase earlier (already drained). Compiler emits exact counted
// lgkmcnt before each MFMA (m97 evidence) — no manual lgkm needed.
//
// Per tile kt (buffer c = kt&1), quadrant order Q00,Q10,Q11,Q01:
//   p1: issue A1c reads (8)          | MFMA Q00(A0,B0)  | BAR
//   p2: issue B1c reads (4); stage A0c,B0c(kt+2)(4 vm) | MFMA Q10(A1,B0) | BAR
//   p3: stage A1c(kt+2)(2 vm)        | MFMA Q11(A1,B1)  | BAR
//   p4: stage B1c(kt+2)(2 vm); VM8; BAR; SB0;
//       issue A0n,B0n reads (12, buffer c^1) | MFMA Q01(A0,B1) | BAR
// Race proofs:
//  - stage X(kt+2) is issued after the barrier following the MFMA whose
//    auto-lgkmcnt enforced X(kt)'s reads complete (A0/B0: consumed p1 ->
//    stage p2; A1: consumed p2 -> stage p3; B1: consumed p3 -> stage p4).
//  - cross-tile reads (p4) only after all waves pass VM8 + barrier:
//    outstanding at VM8 = kt+1's 8 (oldest) + kt+2's 8 (p2:4,p3:2,p4:2)
//    -> vmcnt(8) leaves exactly kt+2's 8 in flight = kt+1 fully in LDS.
//    Counted vmcnt never 0 in main loop (T4).
// A-slot ping-pong (A0 lives p1..p4, next A0 lands in dead A1 slot) ->
// main loop unrolled by 2 with statically swapped slot names (rule #20).
// Registers: afX+afY 64 + b0+b1 32 VGPR + acc 128 (AGPR) ~= 250/wave,
// fits 256 cap at 2 waves/SIMD. T2 swizzle / T5 setprio / epilogue: R5 verbatim.

#define M_TOT 8192
#define N_TOT 4096
#define K_TOT 4096

#define BM 256
#define BN 256
#define BK 64
#define NT (K_TOT / BK)   // 64 K-tiles

typedef __attribute__((ext_vector_type(8))) short short8;
typedef __attribute__((ext_vector_type(4))) float floatx4;

// ---- fp32 -> bf16 round-to-nearest-even ----
__device__ inline unsigned short f2bf(float f) {
    unsigned int u = __builtin_bit_cast(unsigned int, f);
    u += 0x7fffu + ((u >> 16) & 1u);
    return (unsigned short)(u >> 16);
}

// data[M*K] fp32 -> bf16  (exact grid, one float4 per thread)
__global__ __launch_bounds__(256) void cast_data_kernel(const float4* __restrict__ in,
                                                        ushort4* __restrict__ out) {
    int i = blockIdx.x * 256 + threadIdx.x;
    float4 f = in[i];
    ushort4 o;
    o.x = f2bf(f.x); o.y = f2bf(f.y); o.z = f2bf(f.z); o.w = f2bf(f.w);
    out[i] = o;
}

// (weight * mask)[N*K] fp32 -> bf16
__global__ __launch_bounds__(256) void cast_w_kernel(const float4* __restrict__ w,
                                                     const float4* __restrict__ m,
                                                     ushort4* __restrict__ out) {
    int i = blockIdx.x * 256 + threadIdx.x;
    float4 a = w[i];
    float4 b = m[i];
    ushort4 o;
    o.x = f2bf(a.x * b.x); o.y = f2bf(a.y * b.y);
    o.z = f2bf(a.z * b.z); o.w = f2bf(a.w * b.w);
    out[i] = o;
}

// ---- async global->LDS, 16B per lane (LDS dst linear: base + lane*16) ----
__device__ inline void load_lds16(const unsigned short* g, unsigned short* l) {
    __builtin_amdgcn_global_load_lds(
        (__attribute__((address_space(1))) void*)(const_cast<unsigned short*>(g)),
        (__attribute__((address_space(3))) void*)(l),
        16, 0, 0);
}

#define BAR()   __builtin_amdgcn_s_barrier()
#define SB0()   __builtin_amdgcn_sched_barrier(0)
#define VM8()   asm volatile("s_waitcnt vmcnt(8)" ::: "memory")
#define VM0()   asm volatile("s_waitcnt vmcnt(0)" ::: "memory")

__global__ __launch_bounds__(512, 2) void gemm_bt_kernel(const unsigned short* __restrict__ A,
                                                         const unsigned short* __restrict__ W,
                                                         const float* __restrict__ bias,
                                                         float* __restrict__ out) {
    // 2 buffers x 256 rows x 64 cols bf16 for A and B: 64 KiB + 64 KiB.
    __shared__ __align__(16) unsigned short As[2 * BM * BK];
    __shared__ __align__(16) unsigned short Bs[2 * BN * BK];

    const int t = threadIdx.x;
    const int m0 = blockIdx.y * BM;
    const int n0 = blockIdx.x * BN;

    const int lane  = t & 63;
    const int wv    = t >> 6;            // wave 0..7
    const int wm    = (wv >> 2) * 128;   // wave m-offset (0/128)
    const int wn    = (wv & 3) * 64;     // wave n-offset (0/64/128/192)
    const int row16 = lane & 15;
    const int quad  = lane >> 4;         // k-chunk group of this lane
    const int rx    = row16 & 7;         // read-side swizzle factor (== row&7)

    // ---- staging geometry (proven R3/R5 pattern) ----
    // half-tile = 128 rows x 8 slots(16B) = 1024 chunks; thread t writes linear
    // LDS chunks t and t+512. Phys slot (t&7) of row (t>>3) holds logical slot
    // (t&7)^(row&7) => pre-swizzle the GLOBAL source. Row+64: same formula.
    const int srow  = t >> 3;                       // 0..63
    const int lslot = (t & 7) ^ (srow & 7);
    const size_t thr_off = (size_t)srow * K_TOT + (size_t)lslot * 8;  // ushorts

    const unsigned short* Ag = A + (size_t)m0 * K_TOT + thr_off;
    const unsigned short* Bg = W + (size_t)n0 * K_TOT + thr_off;

    auto stageA = [&](int ts, int h) {
        const unsigned short* s = Ag + (size_t)(h * 128) * K_TOT + ts * BK;
        unsigned short* d = As + (ts & 1) * (BM * BK) + h * (128 * BK) + t * 8;
        load_lds16(s, d);
        load_lds16(s + (size_t)64 * K_TOT, d + 512 * 8);
    };
    auto stageB = [&](int ts, int h) {
        const unsigned short* s = Bg + (size_t)(h * 128) * K_TOT + ts * BK;
        unsigned short* d = Bs + (ts & 1) * (BN * BK) + h * (128 * BK) + t * 8;
        load_lds16(s, d);
        load_lds16(s + (size_t)64 * K_TOT, d + 512 * 8);
    };

    // ---- fragment register slots ----
    short8 aX[4][2], aY[4][2];   // two A slots, roles ping-pong per tile (64 VGPR)
    short8 b0[2][2], b1[2][2];   // B halves, fixed roles                (32 VGPR)

    auto readA = [&](int buf, int mh, short8 (&d)[4][2]) {
#pragma unroll
        for (int i = 0; i < 4; i++) {
            const unsigned short* base =
                As + buf * (BM * BK) + (wm + mh * 64 + i * 16 + row16) * BK;
            d[i][0] = *(const short8*)(base + ((quad ^ rx) << 3));
            d[i][1] = *(const short8*)(base + (((4 + quad) ^ rx) << 3));
        }
    };
    auto readB = [&](int buf, int nh, short8 (&d)[2][2]) {
#pragma unroll
        for (int j = 0; j < 2; j++) {
            const unsigned short* base =
                Bs + buf * (BN * BK) + (wn + nh * 32 + j * 16 + row16) * BK;
            d[j][0] = *(const short8*)(base + ((quad ^ rx) << 3));
            d[j][1] = *(const short8*)(base + (((4 + quad) ^ rx) << 3));
        }
    };

    floatx4 acc[8][4];
#pragma unroll
    for (int i = 0; i < 8; i++)
#pragma unroll
        for (int j = 0; j < 4; j++) {
            floatx4 z = {0.0f, 0.0f, 0.0f, 0.0f};
            acc[i][j] = z;
        }

    auto mmaQ = [&](short8 (&a)[4][2], short8 (&b)[2][2], int mh, int nh) {
        __builtin_amdgcn_s_setprio(1);
#pragma unroll
        for (int i = 0; i < 4; i++)
#pragma unroll
            for (int j = 0; j < 2; j++)
#pragma unroll
                for (int ks = 0; ks < 2; ks++)
                    acc[mh * 4 + i][nh * 2 + j] = __builtin_amdgcn_mfma_f32_16x16x32_bf16(
                        a[i][ks], b[j][ks], acc[mh * 4 + i][nh * 2 + j], 0, 0, 0);
        __builtin_amdgcn_s_setprio(0);
    };

    // mode 0: stage kt+2, VM8, cross-tile reads
    // mode 1: no staging, VM0, cross-tile reads (tile NT-2)
    // mode 2: no staging, no waits, no cross reads, no barriers (tile NT-1)
    auto tileT = [&](int kt, short8 (&aC)[4][2], short8 (&aN)[4][2], int mode) {
        const int buf = kt & 1;
        // p1: issue A1c reads | MFMA Q00(aC=A0, b0=B0)
        readA(buf, 1, aN);
        mmaQ(aC, b0, 0, 0);
        if (mode != 2) BAR();
        // p2: issue B1c reads; stage A0c,B0c(kt+2) | MFMA Q10(aN=A1, b0)
        readB(buf, 1, b1);
        if (mode == 0) { stageA(kt + 2, 0); stageB(kt + 2, 0); }
        mmaQ(aN, b0, 1, 0);
        if (mode != 2) BAR();
        // p3: stage A1c(kt+2) | MFMA Q11(aN, b1=B1)
        if (mode == 0) stageA(kt + 2, 1);
        mmaQ(aN, b1, 1, 1);
        if (mode != 2) BAR();
        // p4: stage B1c(kt+2); counted wait; barrier; next-tile A0,B0 reads
        //     into the dead slots (aN, b0) | MFMA Q01(aC, b1)
        if (mode == 0) { stageB(kt + 2, 1); VM8(); }
        else if (mode == 1) { VM0(); }
        if (mode != 2) {
            BAR(); SB0();
            readA(buf ^ 1, 0, aN);
            readB(buf ^ 1, 0, b0);
        }
        mmaQ(aC, b1, 0, 1);
        if (mode != 2) BAR();
    };

    // ---- prologue: stage tiles 0 and 1; tile0 landed; prime A0/B0 reads
    stageA(0, 0); stageB(0, 0); stageA(0, 1); stageB(0, 1);
    stageA(1, 0); stageB(1, 0); stageA(1, 1); stageB(1, 1);
    VM8();
    BAR(); SB0();
    readA(0, 0, aX);
    readB(0, 0, b0);

    // main loop unrolled by 2 for the A-slot ping-pong (NT-2 = 62 tiles, even)
    for (int kt = 0; kt < NT - 2; kt += 2) {
        tileT(kt,     aX, aY, 0);
        tileT(kt + 1, aY, aX, 0);
    }
    tileT(NT - 2, aX, aY, 1);   // drain: VM0, read tile NT-1's A0/B0
    tileT(NT - 1, aY, aX, 2);   // compute only

    // ---- epilogue: C/D layout (16x16x32): col = lane&15, row = (lane>>4)*4 + reg
    float bb[4];
#pragma unroll
    for (int j = 0; j < 4; j++)
        bb[j] = bias[n0 + wn + j * 16 + row16];

#pragma unroll
    for (int ai = 0; ai < 8; ai++) {
        const int gm = m0 + wm + ai * 16 + quad * 4;
#pragma unroll
        for (int bj = 0; bj < 4; bj++) {
            const int gn = n0 + wn + bj * 16 + row16;
            float* o = out + (size_t)gm * N_TOT + gn;
#pragma unroll
            for (int r = 0; r < 4; r++)
                o[(size_t)r * N_TOT] = acc[ai][bj][r] + bb[bj];
        }
    }
}

extern "C" void kernel_launch(void* const* d_in, const int* in_sizes, int n_in,
                              void* d_out, int out_size, void* d_ws, size_t ws_size,
                              hipStream_t stream) {
    const float* data   = (const float*)d_in[0];   // [4,2048,4096]
    const float* weight = (const float*)d_in[1];   // [4096,4096]
    const float* w_mask = (const float*)d_in[2];   // [4096,4096]
    const float* bias_p = (const float*)d_in[3];   // [4096]
    float* out = (float*)d_out;

    // Workspace layout: A_bf16 [M*K] then W_bf16 [N*K]  (96 MB total)
    unsigned short* a_bf = (unsigned short*)d_ws;
    unsigned short* w_bf = a_bf + (size_t)M_TOT * K_TOT;

    cast_data_kernel<<<(M_TOT * K_TOT) / (256 * 4), 256, 0, stream>>>(
        (const float4*)data, (ushort4*)a_bf);
    cast_w_kernel<<<(N_TOT * K_TOT) / (256 * 4), 256, 0, stream>>>(
        (const float4*)weight, (const float4*)w_mask, (ushort4*)w_bf);

    dim3 grid(N_TOT / BN, M_TOT / BM);   // (16, 32)
    gemm_bt_kernel<<<grid, 512, 0, stream>>>(a_bf, w_bf, bias_p, out);
}